// Round 2
// baseline (312.514 us; speedup 1.0000x reference)
//
#include <hip/hip_runtime.h>
#include <hip/hip_bf16.h>

typedef __bf16 bf16x8 __attribute__((ext_vector_type(8)));
typedef float  f32x4  __attribute__((ext_vector_type(4)));

#define B_SZ    1024
#define COUT_SZ 512
#define K_SZ    32768   // G * CIN = 64 * 512
#define TM 128
#define TN 128
#define BK 32

// async 16B global -> LDS (DMA, no VGPR round trip). LDS dest is
// wave-uniform base; HW writes lane l at base + l*16.
__device__ __forceinline__ void async_copy16(const void* g, void* l) {
  __builtin_amdgcn_global_load_lds(
      (const __attribute__((address_space(1))) unsigned int*)g,
      (__attribute__((address_space(3))) unsigned int*)l, 16, 0, 0);
}

// ---------------------------------------------------------------------------
// Prepass: W fp32 [k=g*512+c][o=512] -> Wt bf16 [o=512][k=32768]
// 64x64 tiles through LDS; coalesced fp32 reads, coalesced 16B bf16 writes.
// ---------------------------------------------------------------------------
__global__ __launch_bounds__(256) void wtrans_kernel(
    const float* __restrict__ w, __bf16* __restrict__ wt) {
  __shared__ __bf16 t[64 * 72];  // [o_local][k_local], pitch 72 (16B-aligned rows)
  const int kb = blockIdx.x * 64;
  const int ob = blockIdx.y * 64;
  const int tid = threadIdx.x;

  // load 4 k-rows x 4 o-cols per thread (coalesced: 16 lanes cover 256B of a row)
  const int o4 = (tid & 15) * 4;
  const int k0 = (tid >> 4) * 4;
  const float* src = w + (size_t)(kb + k0) * COUT_SZ + ob + o4;
  f32x4 v0 = *(const f32x4*)(src);
  f32x4 v1 = *(const f32x4*)(src + COUT_SZ);
  f32x4 v2 = *(const f32x4*)(src + 2 * COUT_SZ);
  f32x4 v3 = *(const f32x4*)(src + 3 * COUT_SZ);
#pragma unroll
  for (int c = 0; c < 4; ++c) {
    union { __bf16 h[4]; unsigned long long u; } p;
    p.h[0] = (__bf16)v0[c]; p.h[1] = (__bf16)v1[c];
    p.h[2] = (__bf16)v2[c]; p.h[3] = (__bf16)v3[c];
    *(unsigned long long*)&t[(o4 + c) * 72 + k0] = p.u;  // transposed store, b64
  }
  __syncthreads();

  // write out: thread -> (o_row, 32B k-chunk); 4 lanes cover one 128B row
  const int o  = tid >> 2;
  const int kc = (tid & 3) * 16;
  const uint4* s0 = (const uint4*)&t[o * 72 + kc];
  uint4 a = s0[0];
  uint4 b = s0[1];
  uint4* dst = (uint4*)(wt + (size_t)(ob + o) * K_SZ + kb + kc);
  dst[0] = a;
  dst[1] = b;
}

// ---------------------------------------------------------------------------
// Split-K GEMM: 128x128 tile, BK=32, 256 threads (4 waves, each 64x64 = 4x4
// subtiles of 16x16x32 bf16 MFMA).
//
// LDS layouts are XOR-chunk-swizzled for bank-uniform fragment reads:
//   As: row r (32 fp32 = 8 x 16B chunks): logical chunk c stored at
//       physical chunk c ^ (r & 7).   (unswizzled: all 16 lanes of a quad
//       hit the same 4-bank group -> 16-way conflict, the R1 smoking gun)
//   Bs: row r (32 bf16 = 4 x 16B chunks): logical c at physical c ^ ((r>>1)&3).
// global_load_lds forces lane l -> base + 16*l, so the swizzle is realized by
// permuting each lane's GLOBAL source offset (same address set -> coalescing
// preserved).
// ---------------------------------------------------------------------------
__global__ __launch_bounds__(256, 4)
void gemm_kernel(const float* __restrict__ x, const __bf16* __restrict__ wt,
                 float* __restrict__ dst, int kchunk) {
  __shared__ float  As[TM * BK];   // 16 KB
  __shared__ __bf16 Bs[TN * BK];   // 8 KB

  const int lin = blockIdx.x;
  const int m0 = (lin & 7) * TM;          // 8 m-tiles <-> 8 XCDs (L2 locality)
  const int n0 = ((lin >> 3) & 3) * TN;   // 4 n-tiles
  const int z  = lin >> 5;                // split-K index
  const int tid  = threadIdx.x;
  const int wave = tid >> 6;
  const int lane = tid & 63;

  const int kbase = z * kchunk;

  // --- staging source pointers (swizzled lane->source mapping) ---
  // A issue i: 8 rows x 32 fp32. lane l -> row (l>>3), logical chunk
  // (l&7)^((l>>3)&7)  [so that physical chunk l&7 == logical ^ (row&7)].
  const int aRow = lane >> 3;
  const int aCh  = (lane & 7) ^ (aRow & 7);
  const float* ag0 = x + (size_t)(m0 + (wave * 4 + 0) * 8 + aRow) * K_SZ + kbase + aCh * 4;
  const float* ag1 = x + (size_t)(m0 + (wave * 4 + 1) * 8 + aRow) * K_SZ + kbase + aCh * 4;
  const float* ag2 = x + (size_t)(m0 + (wave * 4 + 2) * 8 + aRow) * K_SZ + kbase + aCh * 4;
  const float* ag3 = x + (size_t)(m0 + (wave * 4 + 3) * 8 + aRow) * K_SZ + kbase + aCh * 4;
  // B issue i: 16 rows x 32 bf16. lane l -> row (l>>2), logical chunk
  // (l&3)^((l>>3)&3)  [physical l&3 == logical ^ ((row>>1)&3)].
  const int bRow = lane >> 2;
  const int bCh  = (lane & 3) ^ ((lane >> 3) & 3);
  const __bf16* bg0 = wt + (size_t)(n0 + (wave * 2 + 0) * 16 + bRow) * K_SZ + kbase + bCh * 8;
  const __bf16* bg1 = wt + (size_t)(n0 + (wave * 2 + 1) * 16 + bRow) * K_SZ + kbase + bCh * 8;

  float* aL0 = &As[(wave * 4 + 0) * 256];
  float* aL1 = &As[(wave * 4 + 1) * 256];
  float* aL2 = &As[(wave * 4 + 2) * 256];
  float* aL3 = &As[(wave * 4 + 3) * 256];
  __bf16* bL0 = &Bs[(wave * 2 + 0) * 512];
  __bf16* bL1 = &Bs[(wave * 2 + 1) * 512];

  // --- fragment geometry ---
  const int lm = lane & 15;      // C/D col, A/B row index within 16
  const int q  = lane >> 4;      // quad: k0 = q*8, C/D row base q*4
  const int wm = (wave & 1) * 64;
  const int wn = (wave >> 1) * 64;

  // swizzled physical chunk indices for fragment reads
  const int aPcLo = (2 * q) ^ (lm & 7);        // logical chunk 2q   of row r (r&7 == lm&7)
  const int bPc   = q ^ ((lm >> 1) & 3);       // logical chunk q    of row r ((r>>1)&3 == (lm>>1)&3)

  f32x4 acc[4][4];
#pragma unroll
  for (int i = 0; i < 4; ++i)
#pragma unroll
    for (int j = 0; j < 4; ++j)
      acc[i][j] = (f32x4){0.f, 0.f, 0.f, 0.f};

  const int niter = kchunk / BK;
  for (int it = 0; it < niter; ++it) {
    async_copy16(ag0, aL0);
    async_copy16(ag1, aL1);
    async_copy16(ag2, aL2);
    async_copy16(ag3, aL3);
    async_copy16(bg0, bL0);
    async_copy16(bg1, bL1);
    ag0 += BK; ag1 += BK; ag2 += BK; ag3 += BK;
    bg0 += BK; bg1 += BK;
    __syncthreads();  // drains vmcnt -> LDS tiles complete

    bf16x8 af[4], bfr[4];
#pragma unroll
    for (int i = 0; i < 4; ++i) {
      const float* rowp = &As[(wm + i * 16 + lm) * BK];
      f32x4 lo = *(const f32x4*)(rowp + aPcLo * 4);
      f32x4 hi = *(const f32x4*)(rowp + (aPcLo ^ 1) * 4);
      bf16x8 a;
#pragma unroll
      for (int e = 0; e < 4; ++e) {
        a[e]     = (__bf16)lo[e];
        a[e + 4] = (__bf16)hi[e];
      }
      af[i] = a;
    }
#pragma unroll
    for (int j = 0; j < 4; ++j)
      bfr[j] = *(const bf16x8*)&Bs[(wn + j * 16 + lm) * BK + bPc * 8];

#pragma unroll
    for (int i = 0; i < 4; ++i)
#pragma unroll
      for (int j = 0; j < 4; ++j)
        acc[i][j] = __builtin_amdgcn_mfma_f32_16x16x32_bf16(af[i], bfr[j], acc[i][j], 0, 0, 0);

    __syncthreads();  // protect LDS from next iter's staging
  }

  // epilogue: C/D layout col=lane&15, row=(lane>>4)*4+reg  [m89-verified]
  float* outp = dst + (size_t)z * (B_SZ * COUT_SZ)
              + (size_t)(m0 + wm + q * 4) * COUT_SZ + (n0 + wn + lm);
#pragma unroll
  for (int i = 0; i < 4; ++i) {
#pragma unroll
    for (int r = 0; r < 4; ++r) {
      float* o2 = outp + (size_t)(i * 16 + r) * COUT_SZ;
#pragma unroll
      for (int j = 0; j < 4; ++j)
        o2[j * 16] = acc[i][j][r];
    }
  }
}

// ---------------------------------------------------------------------------
// Reduce S partial slices + apply 1/sqrt(512) scale.
// ---------------------------------------------------------------------------
__global__ __launch_bounds__(256) void reduce_kernel(
    const float* __restrict__ p, float* __restrict__ out, int S, float scale) {
  const int i = (blockIdx.x * 256 + threadIdx.x) * 4;
  f32x4 s = (f32x4){0.f, 0.f, 0.f, 0.f};
  for (int zz = 0; zz < S; ++zz) {
    f32x4 v = *(const f32x4*)(p + (size_t)zz * (B_SZ * COUT_SZ) + i);
    s = s + v;
  }
  s = s * scale;
  *(f32x4*)(out + i) = s;
}

extern "C" void kernel_launch(void* const* d_in, const int* in_sizes, int n_in,
                              void* d_out, int out_size, void* d_ws, size_t ws_size,
                              hipStream_t stream) {
  const float* x = (const float*)d_in[0];
  const float* w = (const float*)d_in[1];
  float* out = (float*)d_out;

  const size_t wtB    = (size_t)COUT_SZ * K_SZ * sizeof(__bf16);   // 33.5 MB
  const size_t sliceB = (size_t)B_SZ * COUT_SZ * sizeof(float);    // 2 MB

  __bf16* wt = (__bf16*)d_ws;
  int S = 32;  // 1024 blocks = 4/CU (LDS 24KB allows 6); kchunk = 1024
  while (S > 1 && wtB + (size_t)S * sliceB > ws_size) S >>= 1;
  float* partials = (float*)((char*)d_ws + wtB);
  if (wtB + sliceB > ws_size) { partials = out; S = 1; }  // last resort

  const float scale = 0.04419417382415922f;  // 1/sqrt(512)

  hipLaunchKernelGGL(wtrans_kernel, dim3(K_SZ / 64, COUT_SZ / 64), dim3(256), 0,
                     stream, w, wt);
  hipLaunchKernelGGL(gemm_kernel, dim3(32 * S), dim3(256), 0, stream,
                     x, wt, partials, K_SZ / S);
  hipLaunchKernelGGL(reduce_kernel, dim3(B_SZ * COUT_SZ / 1024), dim3(256), 0,
                     stream, partials, out, S, scale);
}

// Round 3
// 302.217 us; speedup vs baseline: 1.0341x; 1.0341x over previous
//
#include <hip/hip_runtime.h>
#include <hip/hip_bf16.h>

typedef __bf16 bf16x8 __attribute__((ext_vector_type(8)));
typedef __bf16 bf16x4 __attribute__((ext_vector_type(4)));
typedef float  f32x4  __attribute__((ext_vector_type(4)));

#define B_SZ    1024
#define COUT_SZ 512
#define K_SZ    32768   // G * CIN = 64 * 512
#define TM 256
#define TN 256
#define BK 32

// async 16B global -> LDS DMA. LDS dest is wave-uniform base; lane l lands at
// base + 16*l.
__device__ __forceinline__ void async_copy16(const void* g, void* l) {
  __builtin_amdgcn_global_load_lds(
      (const __attribute__((address_space(1))) unsigned int*)g,
      (__attribute__((address_space(3))) unsigned int*)l, 16, 0, 0);
}

// ---------------------------------------------------------------------------
// Prepass: W fp32 [k][o] -> Wt bf16 [o][k]. 64x64 tiles via fp32 LDS with
// pitch 65 (65 mod 32 == 1): both phases verified <=2-way bank aliasing
// (free per m136). R2's pitch-72-bf16 layout was 8-16-way conflicted -> this
// kernel was the hidden ~100us.
// ---------------------------------------------------------------------------
__global__ __launch_bounds__(256) void wtrans_kernel(
    const float* __restrict__ w, __bf16* __restrict__ wt) {
  __shared__ float t[64 * 65];
  const int kb = blockIdx.x * 64;
  const int ob = blockIdx.y * 64;
  const int tid = threadIdx.x;

  {  // load: lanes 0-15 cover 256B of one row -> fully coalesced
    const int o4 = (tid & 15) * 4;
    const int kr = tid >> 4;  // 0..15
    const float* src = w + (size_t)(kb + kr) * COUT_SZ + ob + o4;
#pragma unroll
    for (int i = 0; i < 4; ++i) {
      f32x4 v = *(const f32x4*)(src + (size_t)(16 * i) * COUT_SZ);
      *(f32x4*)&t[(kr + 16 * i) * 65 + o4] = v;  // bank = k + o (mod 32): 2-way
    }
  }
  __syncthreads();
  {  // store: 16 lanes x 8B contiguous = 128B coalesced writes
    const int k4 = (tid & 15) * 4;
    const int orow = tid >> 4;  // 0..15
#pragma unroll
    for (int j = 0; j < 4; ++j) {
      const int o = orow + 16 * j;
      bf16x4 p;
#pragma unroll
      for (int e = 0; e < 4; ++e) p[e] = (__bf16)t[(k4 + e) * 65 + o];
      *(bf16x4*)(wt + (size_t)(ob + o) * K_SZ + kb + k4) = p;
    }
  }
}

// ---------------------------------------------------------------------------
// Split-K GEMM, 256x256 tile, 512 threads (8 waves, each 128x64 = 8x4
// subtiles of 16x16x32 bf16 MFMA), BK=32, double-buffered LDS (96 KB,
// 1 block/CU).
//
// Pipeline: barrier drains buf p's DMA; THEN issue buf p^1; THEN compute
// from p -> next-iter loads are in flight during compute (the m97-structure
// vmcnt(0)-drain only pays latency minus compute).
//
// Block mapping lin = z + S*t: XCD = lin%8 = z%8, so all 8 out-tiles of a
// given z co-reside on one XCD -> x-chunk shared x2 (n-tiles) and Wt-chunk
// shared x4 (m-tiles) through that XCD's L2 (per-iter unique bytes/XCD
// ~640 KB << 4 MB).
//
// LDS XOR-chunk swizzle (16B chunks), realized on the global source side
// (global_load_lds pins lane->LDS offset):
//   As row r (8 chunks):  phys = logical ^ (r & 7)
//   Bs row r (4 chunks):  phys = logical ^ ((r >> 1) & 3)
// Both fragment-read patterns verified 2-way max (= wave64 floor).
// ---------------------------------------------------------------------------
__global__ __launch_bounds__(512, 2)
void gemm_kernel(const float* __restrict__ x, const __bf16* __restrict__ wt,
                 float* __restrict__ dst, int kchunk, int S) {
  __shared__ float  Asm[2][TM * BK];   // 2 x 32 KB fp32
  __shared__ __bf16 Bsm[2][TN * BK];   // 2 x 16 KB bf16

  const int lin = blockIdx.x;
  const int z = lin % S;
  const int t = lin / S;
  const int m0 = (t & 3) * TM;
  const int n0 = (t >> 2) * TN;
  const int tid  = threadIdx.x;
  const int w    = tid >> 6;   // 0..7
  const int lane = tid & 63;

  const int kbase = z * kchunk;

  // --- staging sources (XOR-swizzled lane->global mapping) ---
  const int aRow = lane >> 3;                       // 0..7
  const int aCh  = (lane & 7) ^ aRow;               // phys chunk lane&7 == logical ^ (row&7)
  const float* ag0 = x + (size_t)(m0 + (w * 4 + 0) * 8 + aRow) * K_SZ + kbase + aCh * 4;
  const float* ag1 = x + (size_t)(m0 + (w * 4 + 1) * 8 + aRow) * K_SZ + kbase + aCh * 4;
  const float* ag2 = x + (size_t)(m0 + (w * 4 + 2) * 8 + aRow) * K_SZ + kbase + aCh * 4;
  const float* ag3 = x + (size_t)(m0 + (w * 4 + 3) * 8 + aRow) * K_SZ + kbase + aCh * 4;
  const int bRow = lane >> 2;                       // 0..15
  const int bCh  = (lane & 3) ^ ((lane >> 3) & 3);
  const __bf16* bg0 = wt + (size_t)(n0 + (w * 2 + 0) * 16 + bRow) * K_SZ + kbase + bCh * 8;
  const __bf16* bg1 = wt + (size_t)(n0 + (w * 2 + 1) * 16 + bRow) * K_SZ + kbase + bCh * 8;

  // --- fragment geometry ---
  const int lm = lane & 15;
  const int q  = lane >> 4;
  const int wm = (w & 1) * 128;
  const int wn = (w >> 1) * 64;
  const int aPcLo = (2 * q) ^ (lm & 7);
  const int bPc   = q ^ ((lm >> 1) & 3);

  f32x4 acc[8][4];
#pragma unroll
  for (int i = 0; i < 8; ++i)
#pragma unroll
    for (int j = 0; j < 4; ++j)
      acc[i][j] = (f32x4){0.f, 0.f, 0.f, 0.f};

  // prologue: fill buffer 0
  async_copy16(ag0, &Asm[0][(w * 4 + 0) * 256]);
  async_copy16(ag1, &Asm[0][(w * 4 + 1) * 256]);
  async_copy16(ag2, &Asm[0][(w * 4 + 2) * 256]);
  async_copy16(ag3, &Asm[0][(w * 4 + 3) * 256]);
  async_copy16(bg0, &Bsm[0][(w * 2 + 0) * 512]);
  async_copy16(bg1, &Bsm[0][(w * 2 + 1) * 512]);
  ag0 += BK; ag1 += BK; ag2 += BK; ag3 += BK; bg0 += BK; bg1 += BK;

  const int niter = kchunk / BK;
  for (int it = 0; it < niter; ++it) {
    __syncthreads();  // drains this iter's DMA (vmcnt) + orders LDS reuse
    const int p = it & 1;
    if (it + 1 < niter) {
      const int np = p ^ 1;
      async_copy16(ag0, &Asm[np][(w * 4 + 0) * 256]);
      async_copy16(ag1, &Asm[np][(w * 4 + 1) * 256]);
      async_copy16(ag2, &Asm[np][(w * 4 + 2) * 256]);
      async_copy16(ag3, &Asm[np][(w * 4 + 3) * 256]);
      async_copy16(bg0, &Bsm[np][(w * 2 + 0) * 512]);
      async_copy16(bg1, &Bsm[np][(w * 2 + 1) * 512]);
      ag0 += BK; ag1 += BK; ag2 += BK; ag3 += BK; bg0 += BK; bg1 += BK;
    }

    const float*  A_ = Asm[p];
    const __bf16* B_ = Bsm[p];
    bf16x8 bfr[4];
#pragma unroll
    for (int j = 0; j < 4; ++j)
      bfr[j] = *(const bf16x8*)&B_[(wn + j * 16 + lm) * BK + bPc * 8];

#pragma unroll
    for (int i = 0; i < 8; ++i) {
      const float* rowp = &A_[(wm + i * 16 + lm) * BK];
      f32x4 lo = *(const f32x4*)(rowp + aPcLo * 4);
      f32x4 hi = *(const f32x4*)(rowp + (aPcLo ^ 1) * 4);
      bf16x8 a;
#pragma unroll
      for (int e = 0; e < 4; ++e) {
        a[e]     = (__bf16)lo[e];
        a[e + 4] = (__bf16)hi[e];
      }
#pragma unroll
      for (int j = 0; j < 4; ++j)
        acc[i][j] = __builtin_amdgcn_mfma_f32_16x16x32_bf16(a, bfr[j], acc[i][j], 0, 0, 0);
    }
  }

  // epilogue: C/D layout col=lane&15, row=(lane>>4)*4+reg  [m89-verified]
  float* outp = dst + (size_t)z * (B_SZ * COUT_SZ)
              + (size_t)(m0 + wm + q * 4) * COUT_SZ + (n0 + wn + lm);
#pragma unroll
  for (int i = 0; i < 8; ++i) {
#pragma unroll
    for (int r = 0; r < 4; ++r) {
      float* o2 = outp + (size_t)(i * 16 + r) * COUT_SZ;
#pragma unroll
      for (int j = 0; j < 4; ++j)
        o2[j * 16] = acc[i][j][r];
    }
  }
}

// ---------------------------------------------------------------------------
// Reduce S partial slices + scale by 1/sqrt(512).
// ---------------------------------------------------------------------------
__global__ __launch_bounds__(256) void reduce_kernel(
    const float* __restrict__ p, float* __restrict__ out, int S, float scale) {
  const int i = (blockIdx.x * 256 + threadIdx.x) * 4;
  f32x4 s0 = (f32x4){0.f, 0.f, 0.f, 0.f};
  f32x4 s1 = (f32x4){0.f, 0.f, 0.f, 0.f};
  int zz = 0;
  for (; zz + 1 < S; zz += 2) {
    s0 = s0 + *(const f32x4*)(p + (size_t)zz * (B_SZ * COUT_SZ) + i);
    s1 = s1 + *(const f32x4*)(p + (size_t)(zz + 1) * (B_SZ * COUT_SZ) + i);
  }
  for (; zz < S; ++zz)
    s0 = s0 + *(const f32x4*)(p + (size_t)zz * (B_SZ * COUT_SZ) + i);
  s0 = (s0 + s1) * scale;
  *(f32x4*)(out + i) = s0;
}

extern "C" void kernel_launch(void* const* d_in, const int* in_sizes, int n_in,
                              void* d_out, int out_size, void* d_ws, size_t ws_size,
                              hipStream_t stream) {
  const float* x = (const float*)d_in[0];
  const float* w = (const float*)d_in[1];
  float* out = (float*)d_out;

  const size_t wtB    = (size_t)COUT_SZ * K_SZ * sizeof(__bf16);   // 33.5 MB
  const size_t sliceB = (size_t)B_SZ * COUT_SZ * sizeof(float);    // 2 MB

  __bf16* wt = (__bf16*)d_ws;
  int S = 32;  // grid 256 = exactly 1 block/CU; kchunk = 1024 (32 iters)
  while (S > 1 && wtB + (size_t)S * sliceB > ws_size) S >>= 1;
  float* partials = (float*)((char*)d_ws + wtB);

  const float scale = 0.04419417382415922f;  // 1/sqrt(512)

  hipLaunchKernelGGL(wtrans_kernel, dim3(K_SZ / 64, COUT_SZ / 64), dim3(256), 0,
                     stream, w, wt);
  hipLaunchKernelGGL(gemm_kernel, dim3(8 * S), dim3(512), 0, stream,
                     x, wt, partials, K_SZ / S, S);
  hipLaunchKernelGGL(reduce_kernel, dim3(B_SZ * COUT_SZ / 1024), dim3(256), 0,
                     stream, partials, out, S, scale);
}